// Round 1
// 821.283 us; speedup vs baseline: 1.2176x; 1.2176x over previous
//
#include <hip/hip_runtime.h>
#include <hip/hip_bf16.h>
#include <cmath>

// Problem: CPL_MoE  B=32, L=64, H=1024, E=8, K=2, V=12000, OUT=16
#define B_   32
#define L_   64
#define H_   1024
#define E_   8
#define V_   12000
#define OUT_ 16
#define HID_ 512

#define BN  96   // v-tile per block (125 tiles * 96 = 12000 exactly)
#define BK  64   // k-tile
#define LDK 72   // padded LDS row stride (fallback kernel)

#define COMP_OFF 512                      // d_out: [0,512) gauss_param
#define LOSS_OFF (512 + B_ * L_ * V_)     // last element: moe_loss

using f32x4  = __attribute__((ext_vector_type(4))) float;
using bf16x8 = __attribute__((ext_vector_type(8))) short;
using s16x4  = __attribute__((ext_vector_type(4))) short;

__device__ __forceinline__ short f2bf(float f) {
  unsigned u = __builtin_bit_cast(unsigned, f);
  u = (u + 0x7FFFu + ((u >> 16) & 1u)) >> 16;   // round-to-nearest-even
  return (short)u;
}

// async global->LDS DMA, 16 B per lane. dst must be (wave-uniform base + lane*16),
// which our per-thread dst pointers satisfy by construction.
typedef __attribute__((address_space(1))) void gvoid_t;
typedef __attribute__((address_space(3))) void lvoid_t;
#define GLOAD16(g, l) __builtin_amdgcn_global_load_lds((gvoid_t*)(g), (lvoid_t*)(l), 16, 0, 0)

// ---------------------------------------------------------------------------
// Kernel: f32 -> bf16 bulk convert (8 elems/thread/iter, 16B stores).
// ---------------------------------------------------------------------------
__global__ __launch_bounds__(256) void k_conv(const float* __restrict__ src,
                                              short* __restrict__ dst, int n8) {
  size_t i = (size_t)blockIdx.x * 256 + threadIdx.x;
  const size_t stride = (size_t)gridDim.x * 256;
  for (; i < (size_t)n8; i += stride) {
    const f32x4 a = ((const f32x4*)src)[2 * i];
    const f32x4 b = ((const f32x4*)src)[2 * i + 1];
    bf16x8 o;
    o[0] = f2bf(a[0]); o[1] = f2bf(a[1]); o[2] = f2bf(a[2]); o[3] = f2bf(a[3]);
    o[4] = f2bf(b[0]); o[5] = f2bf(b[1]); o[6] = f2bf(b[2]); o[7] = f2bf(b[3]);
    ((bf16x8*)dst)[i] = o;
  }
}

// ---------------------------------------------------------------------------
// Kernel 1: gating + fused gauss_param. One block per batch row.
// hid = relu(q @ W1 + b1); logits = hid @ W2 + b2; top-2 softmax.
// Then gauss_param[b,o] = sigmoid(h_last . (g1*gw[e1,o]+g2*gw[e2,o]) + mixed b)
// computed 16-threads-per-o (replaces the old single-block k_small).
// ---------------------------------------------------------------------------
__global__ __launch_bounds__(256) void k_gate(
    const float* __restrict__ q,  const float* __restrict__ w1,
    const float* __restrict__ b1, const float* __restrict__ w2,
    const float* __restrict__ b2, const float* __restrict__ h,
    const float* __restrict__ gw, const float* __restrict__ gb,
    float* __restrict__ gates,    float* __restrict__ egate,
    int* __restrict__ eidx,       float* __restrict__ out) {
  __shared__ __align__(16) float qs[H_];
  __shared__ __align__(16) float hid[HID_];
  __shared__ __align__(16) float red[256][8];
  __shared__ float sg[2];
  __shared__ int   se[2];
  const int t = threadIdx.x;
  const int b = blockIdx.x;

  ((f32x4*)qs)[t] = ((const f32x4*)(q + (size_t)b * H_))[t];
  __syncthreads();

  // hid: thread -> 4 consecutive j's (jq = t&127), i-range halved (ih = t>>7)
  {
    const int jq = t & 127, ih = t >> 7;
    f32x4 acc = {0.f, 0.f, 0.f, 0.f};
    const float* wp = w1 + (size_t)(ih * 512) * HID_ + 4 * jq;
    for (int i = 0; i < 512; ++i) {
      acc += qs[ih * 512 + i] * *(const f32x4*)(wp + (size_t)i * HID_);
    }
    *(f32x4*)&red[t][0] = acc;
  }
  __syncthreads();
  if (t < 128) {
    f32x4 a = *(f32x4*)&red[t][0];
    a += *(f32x4*)&red[t + 128][0];
    a += *(const f32x4*)(b1 + 4 * t);
    f32x4 r;
    #pragma unroll
    for (int c = 0; c < 4; ++c) r[c] = fmaxf(a[c], 0.f);
    *(f32x4*)&hid[4 * t] = r;
  }
  __syncthreads();

  // logits partials: thread t covers j = t and j = t+256
  {
    const float h0 = hid[t], h1 = hid[t + 256];
    const float* w2a = w2 + (size_t)t * E_;
    const float* w2b = w2 + (size_t)(t + 256) * E_;
    #pragma unroll
    for (int e = 0; e < 8; ++e) red[t][e] = h0 * w2a[e] + h1 * w2b[e];
  }
  __syncthreads();
  for (int s = 128; s > 0; s >>= 1) {
    if (t < s) {
      #pragma unroll
      for (int e = 0; e < 8; ++e) red[t][e] += red[t + s][e];
    }
    __syncthreads();
  }

  if (t == 0) {
    float lg[8];
    #pragma unroll
    for (int e = 0; e < 8; ++e) lg[e] = red[0][e] + b2[e];
    int e1 = 0;
    #pragma unroll
    for (int e = 1; e < 8; ++e) if (lg[e] > lg[e1]) e1 = e;     // lowest idx wins ties
    int e2 = (e1 == 0) ? 1 : 0;
    #pragma unroll
    for (int e = 0; e < 8; ++e) if (e != e1 && lg[e] > lg[e2]) e2 = e;
    const float x2 = expf(lg[e2] - lg[e1]);   // softmax over [lg[e1], lg[e2]]
    const float g1 = 1.f / (1.f + x2);
    const float g2 = x2 / (1.f + x2);
    #pragma unroll
    for (int e = 0; e < 8; ++e)
      gates[b * E_ + e] = (e == e1) ? g1 : (e == e2) ? g2 : 0.f;
    egate[2 * b] = g1; egate[2 * b + 1] = g2;
    eidx[2 * b]  = e1; eidx[2 * b + 1]  = e2;
    sg[0] = g1; sg[1] = g2; se[0] = e1; se[1] = e2;
  }
  __syncthreads();

  // fused gauss_param: o = t>>4 (16 outputs), sub = t&15 splits H into 64-chunks
  {
    const float gg1 = sg[0], gg2 = sg[1];
    const int ee1 = se[0], ee2 = se[1];
    const int o = t >> 4, sub = t & 15;
    const float* hl = h  + ((size_t)(b * L_ + (L_ - 1))) * H_ + sub * 64;
    const float* wa = gw + ((size_t)(ee1 * OUT_ + o)) * H_ + sub * 64;
    const float* wb = gw + ((size_t)(ee2 * OUT_ + o)) * H_ + sub * 64;
    float p = 0.f;
    #pragma unroll 4
    for (int i = 0; i < 64; i += 4) {
      const f32x4 hv = *(const f32x4*)(hl + i);
      const f32x4 va = *(const f32x4*)(wa + i);
      const f32x4 vb = *(const f32x4*)(wb + i);
      const f32x4 w  = gg1 * va + gg2 * vb;
      p += hv[0] * w[0] + hv[1] * w[1] + hv[2] * w[2] + hv[3] * w[3];
    }
    float* red1 = &red[0][0];
    red1[t] = p;
    __syncthreads();
    if (t < 16) {
      float s = gg1 * gb[ee1 * OUT_ + t] + gg2 * gb[ee2 * OUT_ + t];
      #pragma unroll
      for (int k2 = 0; k2 < 16; ++k2) s += red1[t * 16 + k2];
      out[b * OUT_ + t] = 1.f / (1.f + expf(-s));
    }
  }
}

// ---------------------------------------------------------------------------
// Kernel: moe_loss only (needs all b's gates). Trivial.
// ---------------------------------------------------------------------------
__global__ __launch_bounds__(64) void k_loss(const float* __restrict__ gates,
                                             float* __restrict__ out) {
  __shared__ float imp[8];
  const int t = threadIdx.x;
  if (t < 8) {
    float s = 0.f;
    for (int b = 0; b < B_; ++b) s += gates[b * E_ + t];
    imp[t] = s;
  }
  __syncthreads();
  if (t == 0) {
    float m = 0.f;
    #pragma unroll
    for (int e = 0; e < 8; ++e) m += imp[e];
    m *= 0.125f;
    float var = 0.f;
    #pragma unroll
    for (int e = 0; e < 8; ++e) { const float d = imp[e] - m; var += d * d; }
    var *= (1.f / 7.f);
    out[LOSS_OFF] = sqrtf(var) / (m + 1e-10f) * 0.1f;
  }
}

// ---------------------------------------------------------------------------
// Kernel 3 (fast): comp as pure bf16 dual-expert GEMM.
// Block = (b, v-tile 96). K=1024 once; acc1 vs W_e1, acc2 vs W_e2; gates
// applied in f32 epilogue (no in-loop mixing/converting).
// Staging: global_load_lds 16B DMA, linear LDS dest, inverse-swizzled global
// source, XOR-swizzled ds_read (byte ^= (row&7)<<4) -> conflict-free b128.
// Wave w: M-half mh=w&1 (32 rows), N-group ng=w>>1 (3x16 cols).
// ---------------------------------------------------------------------------
__global__ __launch_bounds__(256) void k_comp_fast(
    const short* __restrict__ hbf, const short* __restrict__ wbf,
    const float* __restrict__ cb,  const float* __restrict__ egate,
    const int* __restrict__ eidx,  float* __restrict__ out) {
  __shared__ __align__(16) short As [64 * 64];   // 8 KB
  __shared__ __align__(16) short Bs1[96 * 64];   // 12 KB
  __shared__ __align__(16) short Bs2[96 * 64];   // 12 KB
  const int t  = threadIdx.x;
  const int b  = blockIdx.x;
  const int vt = blockIdx.y;
  const int e1 = eidx[2 * b], e2 = eidx[2 * b + 1];
  const float g1 = egate[2 * b], g2 = egate[2 * b + 1];

  // --- staging source/dest (row = t>>3 within 32-row issue, chunk = t&7) ---
  const int srow = t >> 3, schunk = t & 7;
  const unsigned sxor = (unsigned)((srow & 7) << 4);
  const unsigned soff = (unsigned)((schunk << 4) ^ sxor);   // inverse-swizzled
  const char* sA  = (const char*)hbf + ((size_t)b * 64 + srow) * 2048 + soff;
  const char* sB1 = (const char*)wbf + ((size_t)e1 * V_ + (size_t)vt * 96 + srow) * 2048 + soff;
  const char* sB2 = (const char*)wbf + ((size_t)e2 * V_ + (size_t)vt * 96 + srow) * 2048 + soff;
  char* dA  = (char*)As  + t * 16;
  char* dB1 = (char*)Bs1 + t * 16;
  char* dB2 = (char*)Bs2 + t * 16;

  // --- mfma geometry ---
  const int lane = t & 63, wv = t >> 6;
  const int lr = lane & 15, quad = lane >> 4;
  const int mh = wv & 1, ng = wv >> 1;
  int offA[2][2], offB[3][2];   // [frag][ks] in shorts; fully unrolled indexing
  #pragma unroll
  for (int mf = 0; mf < 2; ++mf) {
    const int ra = mh * 32 + mf * 16 + lr;
    offA[mf][0] = ra * 64 + (((quad    ) ^ (ra & 7)) << 3);
    offA[mf][1] = ra * 64 + (((quad ^ 4) ^ (ra & 7)) << 3);
  }
  #pragma unroll
  for (int nn = 0; nn < 3; ++nn) {
    const int rb = (ng * 3 + nn) * 16 + lr;
    offB[nn][0] = rb * 64 + (((quad    ) ^ (rb & 7)) << 3);
    offB[nn][1] = rb * 64 + (((quad ^ 4) ^ (rb & 7)) << 3);
  }

  f32x4 acc1[2][3], acc2[2][3];
  #pragma unroll
  for (int i = 0; i < 2; ++i)
    #pragma unroll
    for (int j = 0; j < 3; ++j) {
      acc1[i][j] = (f32x4){0.f, 0.f, 0.f, 0.f};
      acc2[i][j] = (f32x4){0.f, 0.f, 0.f, 0.f};
    }

  for (int k0 = 0; k0 < H_; k0 += 64) {
    // stage: A 8 KB (2 issues), B1/B2 12 KB each (3 issues) — pure DMA
    GLOAD16(sA,           dA);
    GLOAD16(sA + 65536,   dA + 4096);
    GLOAD16(sB1,          dB1);
    GLOAD16(sB1 + 65536,  dB1 + 4096);
    GLOAD16(sB1 + 131072, dB1 + 8192);
    GLOAD16(sB2,          dB2);
    GLOAD16(sB2 + 65536,  dB2 + 4096);
    GLOAD16(sB2 + 131072, dB2 + 8192);
    sA += 128; sB1 += 128; sB2 += 128;
    __syncthreads();   // compiler drains vmcnt before s_barrier

    #pragma unroll
    for (int ks = 0; ks < 2; ++ks) {
      const bf16x8 a0 = *(const bf16x8*)(As + offA[0][ks]);
      const bf16x8 a1 = *(const bf16x8*)(As + offA[1][ks]);
      #pragma unroll
      for (int nn = 0; nn < 3; ++nn) {
        const bf16x8 wb1 = *(const bf16x8*)(Bs1 + offB[nn][ks]);
        acc1[0][nn] = __builtin_amdgcn_mfma_f32_16x16x32_bf16(a0, wb1, acc1[0][nn], 0, 0, 0);
        acc1[1][nn] = __builtin_amdgcn_mfma_f32_16x16x32_bf16(a1, wb1, acc1[1][nn], 0, 0, 0);
        const bf16x8 wb2 = *(const bf16x8*)(Bs2 + offB[nn][ks]);
        acc2[0][nn] = __builtin_amdgcn_mfma_f32_16x16x32_bf16(a0, wb2, acc2[0][nn], 0, 0, 0);
        acc2[1][nn] = __builtin_amdgcn_mfma_f32_16x16x32_bf16(a1, wb2, acc2[1][nn], 0, 0, 0);
      }
    }
    __syncthreads();
  }

  // epilogue: gates + mixed bias in f32 (D layout: col=lane&15, row=quad*4+r)
  #pragma unroll
  for (int nn = 0; nn < 3; ++nn) {
    const int v = vt * 96 + (ng * 3 + nn) * 16 + lr;
    const float bias = g1 * cb[e1 * V_ + v] + g2 * cb[e2 * V_ + v];
    #pragma unroll
    for (int mf = 0; mf < 2; ++mf) {
      const int lbase = mh * 32 + mf * 16 + quad * 4;
      float* op = out + COMP_OFF + ((size_t)(b * L_ + lbase)) * V_ + v;
      #pragma unroll
      for (int rr = 0; rr < 4; ++rr)
        op[(size_t)rr * V_] = g1 * acc1[mf][nn][rr] + g2 * acc2[mf][nn][rr] + bias;
    }
  }
}

// ---------------------------------------------------------------------------
// Kernel 3 (fallback, used only if workspace too small): previous version.
// ---------------------------------------------------------------------------
__global__ __launch_bounds__(256) void k_comp(
    const float* __restrict__ h,     const float* __restrict__ cw,
    const float* __restrict__ cbp,   const float* __restrict__ egate,
    const int* __restrict__ eidx,    float* __restrict__ out) {
  __shared__ __align__(16) short As[L_ * LDK];
  __shared__ __align__(16) short Bs[BN * LDK];
  const int t  = threadIdx.x;
  const int b  = blockIdx.x;
  const int vt = blockIdx.y;
  const int e1 = eidx[2 * b], e2 = eidx[2 * b + 1];
  const float g1 = egate[2 * b], g2 = egate[2 * b + 1];

  const float* hrow = h + ((size_t)b * L_ + (t >> 2)) * H_ + ((t & 3) * 16);
  const float* w1p  = cw + ((size_t)e1 * V_ + (size_t)vt * BN) * H_;
  const float* w2p  = cw + ((size_t)e2 * V_ + (size_t)vt * BN) * H_;

  f32x4 acc[6];
  #pragma unroll
  for (int i = 0; i < 6; ++i) acc[i] = (f32x4){0.f, 0.f, 0.f, 0.f};

  const int wv = t >> 6;
  const int lane = t & 63;
  const int lr = lane & 15, quad = lane >> 4;
  const short* Ap = As + (wv * 16 + lr) * LDK;
  const short* Bp = Bs + lr * LDK;

  const int wr = t >> 3;
  const int wc = (t & 7) * 8;

  for (int k0 = 0; k0 < H_; k0 += BK) {
    {
      const float* src = hrow + k0;
      short* dst = As + (t >> 2) * LDK + (t & 3) * 16;
      #pragma unroll
      for (int c = 0; c < 16; c += 4) {
        const f32x4 v = *(const f32x4*)(src + c);
        s16x4 sv;
        sv[0] = f2bf(v[0]); sv[1] = f2bf(v[1]);
        sv[2] = f2bf(v[2]); sv[3] = f2bf(v[3]);
        *(s16x4*)(dst + c) = sv;
      }
    }
    #pragma unroll
    for (int p = 0; p < 3; ++p) {
      const int r = p * 32 + wr;
      const float* s1 = w1p + (size_t)r * H_ + k0 + wc;
      const float* s2 = w2p + (size_t)r * H_ + k0 + wc;
      short* dst = Bs + r * LDK + wc;
      #pragma unroll
      for (int c = 0; c < 8; c += 4) {
        const f32x4 a  = *(const f32x4*)(s1 + c);
        const f32x4 bb = *(const f32x4*)(s2 + c);
        const f32x4 m  = g1 * a + g2 * bb;
        s16x4 sv;
        sv[0] = f2bf(m[0]); sv[1] = f2bf(m[1]);
        sv[2] = f2bf(m[2]); sv[3] = f2bf(m[3]);
        *(s16x4*)(dst + c) = sv;
      }
    }
    __syncthreads();

    #pragma unroll
    for (int ks = 0; ks < BK; ks += 32) {
      const bf16x8 af = *(const bf16x8*)(Ap + ks + quad * 8);
      #pragma unroll
      for (int n = 0; n < 6; ++n) {
        const bf16x8 bf = *(const bf16x8*)(Bp + n * 16 * LDK + ks + quad * 8);
        acc[n] = __builtin_amdgcn_mfma_f32_16x16x32_bf16(af, bf, acc[n], 0, 0, 0);
      }
    }
    __syncthreads();
  }

  #pragma unroll
  for (int n = 0; n < 6; ++n) {
    const int v = vt * BN + n * 16 + lr;
    const float bias = g1 * cbp[e1 * V_ + v] + g2 * cbp[e2 * V_ + v];
    #pragma unroll
    for (int r = 0; r < 4; ++r) {
      const int l = wv * 16 + quad * 4 + r;
      out[COMP_OFF + ((size_t)(b * L_ + l)) * V_ + v] = acc[n][r] + bias;
    }
  }
}

// ---------------------------------------------------------------------------
extern "C" void kernel_launch(void* const* d_in, const int* in_sizes, int n_in,
                              void* d_out, int out_size, void* d_ws, size_t ws_size,
                              hipStream_t stream) {
  const float* q   = (const float*)d_in[0];
  const float* h   = (const float*)d_in[1];
  const float* w1  = (const float*)d_in[2];
  const float* b1  = (const float*)d_in[3];
  const float* w2  = (const float*)d_in[4];
  const float* b2  = (const float*)d_in[5];
  const float* gw  = (const float*)d_in[6];
  const float* gb  = (const float*)d_in[7];
  const float* cw  = (const float*)d_in[8];
  const float* cbp = (const float*)d_in[9];
  float* out = (float*)d_out;

  // ws layout: [0,1024) gates/egate/eidx block (floats);
  // [4096, +4MB) h_bf16; then 196.6 MB comp_w bf16 (fast path only).
  float* F     = (float*)d_ws;
  float* gates = F;
  float* egate = F + 256;
  int*   eidx  = (int*)(F + 320);

  const size_t HBF_OFF = 4096;
  const size_t HBF_BYTES = (size_t)B_ * L_ * H_ * 2;           // 4,194,304
  const size_t WBF_OFF = HBF_OFF + HBF_BYTES;
  const size_t WBF_BYTES = (size_t)E_ * V_ * H_ * 2;           // 196,608,000
  const size_t WS_NEED = WBF_OFF + WBF_BYTES;

  k_gate<<<B_, 256, 0, stream>>>(q, w1, b1, w2, b2, h, gw, gb, gates, egate, eidx, out);
  k_loss<<<1, 64, 0, stream>>>(gates, out);

  if (ws_size >= WS_NEED) {
    short* hbf = (short*)((char*)d_ws + HBF_OFF);
    short* wbf = (short*)((char*)d_ws + WBF_OFF);
    k_conv<<<2048, 256, 0, stream>>>(cw, wbf, (int)((size_t)E_ * V_ * H_ / 8));
    k_conv<<<256, 256, 0, stream>>>(h, hbf, (int)((size_t)B_ * L_ * H_ / 8));
    k_comp_fast<<<dim3(B_, V_ / BN), 256, 0, stream>>>(hbf, wbf, cbp, egate, eidx, out);
  } else {
    k_comp<<<dim3(B_, V_ / BN), 256, 0, stream>>>(h, cw, cbp, egate, eidx, out);
  }
}